// Round 5
// baseline (516.218 us; speedup 1.0000x reference)
//
#include <hip/hip_runtime.h>
#include <hip/hip_cooperative_groups.h>

// TinyMambaMulti: B=4, L=4096, D_MODEL=64, D_INNER=128, D_STATE=16, DT_RANK=4,
// D_CONV=4, N_LAYERS=2, OUT=6. All fp32.

#define NB 4
#define SL 4096
#define NC 128           // scan chunks per sequence
#define CT 32            // steps per chunk (NC*CT == SL)

namespace cg = cooperative_groups;

__device__ __forceinline__ float siluf(float x) { return x / (1.f + __expf(-x)); }
__device__ __forceinline__ float softplusf(float x) { return x > 20.f ? x : log1pf(__expf(x)); }

// ---------------- prep: transpose out_proj_w [2][64][128] -> opwT [2][128][64] ----------------
__global__ __launch_bounds__(256) void k_prep(const float* __restrict__ opw, float* __restrict__ opwT) {
  int i = blockIdx.x * 256 + threadIdx.x;   // 16384
  int l = i >> 13;
  int rem = i & 8191;
  int d = rem >> 6, m = rem & 63;
  opwT[i] = opw[l * 8192 + m * 128 + d];
}

// ---------------- linear_in: h[r][64] = x[r][57] @ w[64][57]^T + b ----------------
__global__ __launch_bounds__(256) void k_linin(const float* __restrict__ x, const float* __restrict__ w,
                                               const float* __restrict__ bias, float* __restrict__ h) {
  __shared__ __align__(16) float xs[64][60];
  __shared__ __align__(16) float ws[64][60];
  const int t = threadIdx.x;
  const int r0 = blockIdx.x * 64;
  for (int i = t; i < 64 * 57; i += 256) {
    int r = i / 57, k = i - r * 57;
    xs[r][k] = x[(r0 + r) * 57 + k];
    ws[r][k] = w[i];
  }
  for (int i = t; i < 64 * 3; i += 256) {
    int r = i / 3, j = i - r * 3;
    xs[r][57 + j] = 0.f;
    ws[r][57 + j] = 0.f;
  }
  __syncthreads();
  const int col = t & 63;
  const int rg = t >> 6;
  float wreg[15][4];
#pragma unroll
  for (int k4 = 0; k4 < 15; ++k4) {
    float4 v = *(const float4*)&ws[col][k4 * 4];
    wreg[k4][0] = v.x; wreg[k4][1] = v.y; wreg[k4][2] = v.z; wreg[k4][3] = v.w;
  }
  const float bcol = bias[col];
  for (int g = 0; g < 4; ++g) {
    const int rb = rg * 16 + g * 4;
    float acc[4] = {bcol, bcol, bcol, bcol};
#pragma unroll
    for (int k4 = 0; k4 < 15; ++k4) {
#pragma unroll
      for (int i = 0; i < 4; ++i) {
        float4 xv = *(const float4*)&xs[rb + i][k4 * 4];
        acc[i] = fmaf(xv.x, wreg[k4][0], acc[i]);
        acc[i] = fmaf(xv.y, wreg[k4][1], acc[i]);
        acc[i] = fmaf(xv.z, wreg[k4][2], acc[i]);
        acc[i] = fmaf(xv.w, wreg[k4][3], acc[i]);
      }
    }
#pragma unroll
    for (int i = 0; i < 4; ++i) h[(r0 + rb + i) * 64 + col] = acc[i];
  }
}

// ---------------- in_proj: [16384x256] = h[16384x64] @ W[256x64]^T, split xp/z ----------------
__global__ __launch_bounds__(256) void k_inproj(const float* __restrict__ hin, const float* __restrict__ W,
                                                float* __restrict__ xp, float* __restrict__ z) {
  __shared__ __align__(16) float ht[64][68];
  __shared__ __align__(16) float wt[64][68];
  const int t = threadIdx.x;
  const int r0 = blockIdx.x * 64;
  const int c0 = blockIdx.y * 64;
  for (int idx = t; idx < 64 * 16; idx += 256) {
    int r = idx >> 4, k4 = idx & 15;
    float4 v = *(const float4*)(hin + (r0 + r) * 64 + 4 * k4);
    ht[4 * k4 + 0][r] = v.x; ht[4 * k4 + 1][r] = v.y; ht[4 * k4 + 2][r] = v.z; ht[4 * k4 + 3][r] = v.w;
  }
  for (int idx = t; idx < 64 * 16; idx += 256) {
    int c = idx >> 4, k4 = idx & 15;
    float4 v = *(const float4*)(W + (c0 + c) * 64 + 4 * k4);
    wt[4 * k4 + 0][c] = v.x; wt[4 * k4 + 1][c] = v.y; wt[4 * k4 + 2][c] = v.z; wt[4 * k4 + 3][c] = v.w;
  }
  __syncthreads();
  const int tc = t & 15, tr = t >> 4;
  float acc[4][4] = {};
  for (int k = 0; k < 64; ++k) {
    float4 a = *(const float4*)&ht[k][4 * tr];
    float4 b = *(const float4*)&wt[k][4 * tc];
    float av[4] = {a.x, a.y, a.z, a.w};
    float bv[4] = {b.x, b.y, b.z, b.w};
#pragma unroll
    for (int i = 0; i < 4; ++i)
#pragma unroll
      for (int j = 0; j < 4; ++j) acc[i][j] = fmaf(av[i], bv[j], acc[i][j]);
  }
#pragma unroll
  for (int i = 0; i < 4; ++i) {
    int row = r0 + 4 * tr + i;
    int c = c0 + 4 * tc;
    float4 v = make_float4(acc[i][0], acc[i][1], acc[i][2], acc[i][3]);
    if (c0 < 128) *(float4*)(xp + row * 128 + c) = v;
    else          *(float4*)(z + row * 128 + (c - 128)) = v;
  }
}

// ---------------- k_coop: conv+silu + x_proj + dt_proj + full scan + gate + out_proj + residual ----
// One cooperative kernel per layer. Grid = (NC=128, NB=4) blocks x 256 thr, 2 blocks/CU (LDS 76.4KB).
__global__ __launch_bounds__(256, 2) void k_coop(
    const float* __restrict__ xp, const float* __restrict__ z_g,
    const float* __restrict__ cw, const float* __restrict__ cb,
    const float* __restrict__ xpw, const float* __restrict__ dpw, const float* __restrict__ dpb,
    const float* __restrict__ Alog, const float* __restrict__ Dsk, const float* __restrict__ opwT,
    float* __restrict__ summary, float* __restrict__ dtsumG, float* __restrict__ cinG,
    float* __restrict__ h) {
  __shared__ __align__(16) float ush[32][132];     // 16896 B (persists A->C)
  __shared__ __align__(16) float dsh[32][132];     // 16896 B (persists A->C)
  __shared__ __align__(16) float dbl[32][40];      // 5120 B  (dt-rank 0..3, B 4..19, C 20..35)
  __shared__ __align__(16) char poolX[35 * 132 * 4]; // 18480 B: xpsh[35][132] | ysh[32][132]
  __shared__ __align__(16) char poolW[36 * 132 * 4]; // 19008 B: wsh[36][132]  | ygsh[128][36]

  float* xpsh = (float*)poolX;   // [35][132]
  float* ysh  = (float*)poolX;   // [32][132]
  float* wsh  = (float*)poolW;   // [36][132]
  float* ygsh = (float*)poolW;   // [128][36]

  const int t = threadIdx.x;
  const int c = blockIdx.x;        // chunk 0..127
  const int b = blockIdx.y;        // batch 0..3
  const int grow0 = b * SL + c * CT;
  const int d = t & 127, hf = t >> 7, n0 = hf * 8;

  // ---- Phase A0: stage xp rows [c*CT-3, c*CT+32) and x_proj_w ----
  for (int i = t; i < 35 * 128; i += 256) {
    int r = i >> 7, dd = i & 127;
    float v = 0.f;
    if (!(c == 0 && r < 3)) v = xp[(size_t)(grow0 - 3 + r) * 128 + dd];
    xpsh[r * 132 + dd] = v;
  }
  for (int i = t; i < 36 * 128; i += 256) {
    int cc = i >> 7, dd = i & 127;
    wsh[cc * 132 + dd] = xpw[cc * 128 + dd];
  }
  __syncthreads();

  // ---- Phase A1: conv + silu -> u ----
  for (int i = t; i < 32 * 128; i += 256) {
    int r = i >> 7, dd = i & 127;
    float4 cwv = *(const float4*)(cw + dd * 4);
    float val = cb[dd] + xpsh[r * 132 + dd] * cwv.x + xpsh[(r + 1) * 132 + dd] * cwv.y +
                xpsh[(r + 2) * 132 + dd] * cwv.z + xpsh[(r + 3) * 132 + dd] * cwv.w;
    ush[r][dd] = siluf(val);
  }
  __syncthreads();

  // ---- Phase A2: x_proj -> dbl[32][36] (tasks: 32 rows x 9 col-groups) ----
  for (int idx = t; idx < 32 * 9; idx += 256) {
    int r = idx / 9, cg2 = idx - (idx / 9) * 9;
    int cc = cg2 * 4;
    float a0 = 0, a1 = 0, a2 = 0, a3 = 0;
#pragma unroll 8
    for (int k4 = 0; k4 < 32; ++k4) {
      float4 uu = *(const float4*)&ush[r][4 * k4];
      float4 w0 = *(const float4*)&wsh[(cc + 0) * 132 + 4 * k4];
      float4 w1 = *(const float4*)&wsh[(cc + 1) * 132 + 4 * k4];
      float4 w2 = *(const float4*)&wsh[(cc + 2) * 132 + 4 * k4];
      float4 w3 = *(const float4*)&wsh[(cc + 3) * 132 + 4 * k4];
      a0 += uu.x * w0.x + uu.y * w0.y + uu.z * w0.z + uu.w * w0.w;
      a1 += uu.x * w1.x + uu.y * w1.y + uu.z * w1.z + uu.w * w1.w;
      a2 += uu.x * w2.x + uu.y * w2.y + uu.z * w2.z + uu.w * w2.w;
      a3 += uu.x * w3.x + uu.y * w3.y + uu.z * w3.z + uu.w * w3.w;
    }
    dbl[r][cc + 0] = a0; dbl[r][cc + 1] = a1; dbl[r][cc + 2] = a2; dbl[r][cc + 3] = a3;
  }
  __syncthreads();

  // ---- Phase A3: dt_proj + softplus -> delta ----
  for (int i = t; i < 32 * 128; i += 256) {
    int r = i >> 7, dd = i & 127;
    float4 wv = *(const float4*)(dpw + dd * 4);
    float acc = dpb[dd] + dbl[r][0] * wv.x + dbl[r][1] * wv.y + dbl[r][2] * wv.z + dbl[r][3] * wv.w;
    dsh[r][dd] = softplusf(acc);
  }
  __syncthreads();

  // ---- Phase A4: chunk-local scan; publish Hl + dtsum ----
  float a[8];
#pragma unroll
  for (int j = 0; j < 8; ++j) a[j] = -__expf(Alog[d * 16 + n0 + j]);
  {
    float hst[8] = {};
    float dts = 0.f;
#pragma unroll 4
    for (int tt = 0; tt < CT; ++tt) {
      float dt = dsh[tt][d];
      float du = dt * ush[tt][d];
      dts += dt;
#pragma unroll
      for (int j = 0; j < 8; ++j) {
        float e = __expf(dt * a[j]);
        hst[j] = fmaf(e, hst[j], du * dbl[tt][4 + n0 + j]);
      }
    }
    size_t off = ((size_t)(b * NC + c) * 128 + d) * 16 + n0;
    *(float4*)(summary + off + 0) = make_float4(hst[0], hst[1], hst[2], hst[3]);
    *(float4*)(summary + off + 4) = make_float4(hst[4], hst[5], hst[6], hst[7]);
    if (hf == 0) dtsumG[(b * NC + c) * 128 + d] = dts;
  }

  cg::this_grid().sync();

  // ---- Phase B: carry propagation, 8192 chains of length NC ----
  {
    int gid = (blockIdx.y * gridDim.x + blockIdx.x) * 256 + t;
    if (gid < NB * 128 * 16) {
      int n2 = gid & 15, d2 = (gid >> 4) & 127, b2 = gid >> 11;
      float A2 = -__expf(Alog[d2 * 16 + n2]);
      float carry = 0.f;
#pragma unroll 4
      for (int c2 = 0; c2 < NC; ++c2) {
        size_t base = ((size_t)(b2 * NC + c2) * 128 + d2) * 16 + n2;
        float Hl = summary[base];
        float ds = dtsumG[(b2 * NC + c2) * 128 + d2];
        cinG[base] = carry;
        carry = fmaf(__expf(ds * A2), carry, Hl);
      }
    }
  }

  cg::this_grid().sync();

  // ---- Phase C1: replay scan with carry-in -> yp regs ----
  float yp[CT];
  {
    float hst[8];
    size_t off = ((size_t)(b * NC + c) * 128 + d) * 16 + n0;
    float4 h0 = *(const float4*)(cinG + off + 0);
    float4 h1 = *(const float4*)(cinG + off + 4);
    hst[0] = h0.x; hst[1] = h0.y; hst[2] = h0.z; hst[3] = h0.w;
    hst[4] = h1.x; hst[5] = h1.y; hst[6] = h1.z; hst[7] = h1.w;
#pragma unroll 4
    for (int tt = 0; tt < CT; ++tt) {
      float dt = dsh[tt][d];
      float du = dt * ush[tt][d];
      float yv = 0.f;
#pragma unroll
      for (int j = 0; j < 8; ++j) {
        float e = __expf(dt * a[j]);
        hst[j] = fmaf(e, hst[j], du * dbl[tt][4 + n0 + j]);
        yv = fmaf(hst[j], dbl[tt][20 + n0 + j], yv);
      }
      yp[tt] = yv;
    }
  }
  // combine the two n-halves in ysh (poolX: xpsh dead)
  if (hf == 0) {
#pragma unroll 4
    for (int tt = 0; tt < CT; ++tt) ysh[tt * 132 + d] = yp[tt];
  }
  __syncthreads();
  if (hf == 1) {
#pragma unroll 4
    for (int tt = 0; tt < CT; ++tt) ysh[tt * 132 + d] += yp[tt];
  }
  __syncthreads();

  // ---- Phase C2: D-skip + silu(z) gate -> ygsh[d][r] (poolW: wsh dead) ----
  for (int i = t; i < 32 * 128; i += 256) {
    int r = i >> 7, dd = i & 127;
    float y = ysh[r * 132 + dd] + ush[r][dd] * Dsk[dd];
    float zv = z_g[(size_t)(grow0 + r) * 128 + dd];
    ygsh[dd * 36 + r] = y * siluf(zv);
  }
  __syncthreads();

  // ---- Phase C3: out_proj (full K per thread) + residual ----
  {
    const int o = t & 63, q = t >> 6;     // rows q*8 .. q*8+8
    float acc[8] = {};
    for (int k = 0; k < 128; ++k) {
      float w = opwT[k * 64 + o];
      float4 y0 = *(const float4*)&ygsh[k * 36 + q * 8];
      float4 y1 = *(const float4*)&ygsh[k * 36 + q * 8 + 4];
      acc[0] = fmaf(y0.x, w, acc[0]); acc[1] = fmaf(y0.y, w, acc[1]);
      acc[2] = fmaf(y0.z, w, acc[2]); acc[3] = fmaf(y0.w, w, acc[3]);
      acc[4] = fmaf(y1.x, w, acc[4]); acc[5] = fmaf(y1.y, w, acc[5]);
      acc[6] = fmaf(y1.z, w, acc[6]); acc[7] = fmaf(y1.w, w, acc[7]);
    }
#pragma unroll
    for (int j = 0; j < 8; ++j)
      h[(size_t)(grow0 + q * 8 + j) * 64 + o] += acc[j];
  }
}

// ---------------- pooling partials over L ----------------
__global__ __launch_bounds__(256) void k_poolpart(const float* __restrict__ h, float* __restrict__ pp) {
  const int lb = blockIdx.x;
  const int b = blockIdx.y;
  const int t = threadIdx.x;
  const int d = t & 63, part = t >> 6;
  float s = 0.f;
  for (int i = 0; i < 32; ++i) {
    int l = lb * 128 + part + i * 4;
    s += h[(size_t)(b * SL + l) * 64 + d];
  }
  __shared__ float red[256];
  red[t] = s;
  __syncthreads();
  if (t < 64) pp[(b * 32 + lb) * 64 + t] = red[t] + red[t + 64] + red[t + 128] + red[t + 192];
}

// ---------------- final reduce + classifier ----------------
__global__ __launch_bounds__(256) void k_cls(const float* __restrict__ pp, const float* __restrict__ wc,
                                             const float* __restrict__ bc, float* __restrict__ out) {
  const int t = threadIdx.x;
  __shared__ float pooled[4][64];
  int b = t >> 6, d = t & 63;
  float s = 0.f;
  for (int lb = 0; lb < 32; ++lb) s += pp[(b * 32 + lb) * 64 + d];
  pooled[b][d] = s * (1.f / 4096.f);
  __syncthreads();
  if (t < 24) {
    int bb = t / 6, o = t - bb * 6;
    float acc = bc[o];
    for (int d2 = 0; d2 < 64; ++d2) acc += pooled[bb][d2] * wc[o * 64 + d2];
    out[bb * 6 + o] = acc;
  }
}

extern "C" void kernel_launch(void* const* d_in, const int* in_sizes, int n_in,
                              void* d_out, int out_size, void* d_ws, size_t ws_size,
                              hipStream_t stream) {
  const float* x    = (const float*)d_in[0];
  const float* w_in = (const float*)d_in[1];
  const float* b_in = (const float*)d_in[2];
  const float* ipw  = (const float*)d_in[3];
  const float* cw   = (const float*)d_in[4];
  const float* cb   = (const float*)d_in[5];
  const float* xpw  = (const float*)d_in[6];
  const float* dpw  = (const float*)d_in[7];
  const float* dpb  = (const float*)d_in[8];
  const float* Alog = (const float*)d_in[9];
  const float* Dsk  = (const float*)d_in[10];
  const float* opw  = (const float*)d_in[11];
  const float* wc   = (const float*)d_in[12];
  const float* bc   = (const float*)d_in[13];
  float* out = (float*)d_out;

  float* ws      = (float*)d_ws;
  float* h       = ws;                    // 1048576
  float* xp      = h + 1048576;           // 2097152
  float* zb      = xp + 2097152;          // 2097152
  float* summary = zb + 2097152;          // 1048576 (4*128*128*16)
  float* dtsum   = summary + 1048576;     // 65536   (4*128*128)
  float* cin     = dtsum + 65536;         // 1048576
  float* opwT    = cin + 1048576;         // 16384
  float* pp      = opwT + 16384;          // 8192

  k_prep<<<64, 256, 0, stream>>>(opw, opwT);
  k_linin<<<256, 256, 0, stream>>>(x, w_in, b_in, h);
  for (int i = 0; i < 2; ++i) {
    k_inproj<<<dim3(256, 4), 256, 0, stream>>>(h, ipw + i * 16384, xp, zb);
    const float* cwi  = cw + i * 512;
    const float* cbi  = cb + i * 128;
    const float* xpwi = xpw + i * 4608;
    const float* dpwi = dpw + i * 512;
    const float* dpbi = dpb + i * 128;
    const float* Ali  = Alog + i * 2048;
    const float* Dsi  = Dsk + i * 128;
    const float* opTi = opwT + i * 8192;
    void* coopArgs[] = {
      (void*)&xp, (void*)&zb, (void*)&cwi, (void*)&cbi, (void*)&xpwi,
      (void*)&dpwi, (void*)&dpbi, (void*)&Ali, (void*)&Dsi, (void*)&opTi,
      (void*)&summary, (void*)&dtsum, (void*)&cin, (void*)&h
    };
    hipLaunchCooperativeKernel((const void*)k_coop, dim3(NC, NB), dim3(256),
                               coopArgs, 0, stream);
  }
  k_poolpart<<<dim3(32, 4), 256, 0, stream>>>(h, pp);
  k_cls<<<1, 256, 0, stream>>>(pp, wc, bc, out);
}

// Round 6
// 246.696 us; speedup vs baseline: 2.0925x; 2.0925x over previous
//
#include <hip/hip_runtime.h>

// TinyMambaMulti: B=4, L=4096, D_MODEL=64, D_INNER=128, D_STATE=16, DT_RANK=4,
// D_CONV=4, N_LAYERS=2, OUT=6. All fp32.
// Latency-bound workload: split kernels, max occupancy. No cooperative launch
// (round-5 coop fusion regressed: 2 blocks/CU co-residency + scratch spill).

#define NB 4
#define SL 4096
#define NC 256           // scan chunks per sequence
#define CT 16            // steps per chunk (NC*CT == SL)

__device__ __forceinline__ float siluf(float x) { return x / (1.f + __expf(-x)); }
__device__ __forceinline__ float softplusf(float x) { return x > 20.f ? x : log1pf(__expf(x)); }

// ---------------- prep: transpose out_proj_w [2][64][128] -> opwT [2][128][64] ----------------
__global__ __launch_bounds__(256) void k_prep(const float* __restrict__ opw, float* __restrict__ opwT) {
  int i = blockIdx.x * 256 + threadIdx.x;   // 16384
  int l = i >> 13;
  int rem = i & 8191;
  int d = rem >> 6, m = rem & 63;
  opwT[i] = opw[l * 8192 + m * 128 + d];
}

// ---------------- linear_in: h[r][64] = x[r][57] @ w[64][57]^T + b ----------------
__global__ __launch_bounds__(256) void k_linin(const float* __restrict__ x, const float* __restrict__ w,
                                               const float* __restrict__ bias, float* __restrict__ h) {
  __shared__ __align__(16) float xs[64][60];
  __shared__ __align__(16) float ws[64][60];
  const int t = threadIdx.x;
  const int r0 = blockIdx.x * 64;
  for (int i = t; i < 64 * 57; i += 256) {
    int r = i / 57, k = i - r * 57;
    xs[r][k] = x[(r0 + r) * 57 + k];
    ws[r][k] = w[i];
  }
  for (int i = t; i < 64 * 3; i += 256) {
    int r = i / 3, j = i - r * 3;
    xs[r][57 + j] = 0.f;
    ws[r][57 + j] = 0.f;
  }
  __syncthreads();
  const int col = t & 63;
  const int rg = t >> 6;
  float wreg[15][4];
#pragma unroll
  for (int k4 = 0; k4 < 15; ++k4) {
    float4 v = *(const float4*)&ws[col][k4 * 4];
    wreg[k4][0] = v.x; wreg[k4][1] = v.y; wreg[k4][2] = v.z; wreg[k4][3] = v.w;
  }
  const float bcol = bias[col];
  for (int g = 0; g < 4; ++g) {
    const int rb = rg * 16 + g * 4;
    float acc[4] = {bcol, bcol, bcol, bcol};
#pragma unroll
    for (int k4 = 0; k4 < 15; ++k4) {
#pragma unroll
      for (int i = 0; i < 4; ++i) {
        float4 xv = *(const float4*)&xs[rb + i][k4 * 4];
        acc[i] = fmaf(xv.x, wreg[k4][0], acc[i]);
        acc[i] = fmaf(xv.y, wreg[k4][1], acc[i]);
        acc[i] = fmaf(xv.z, wreg[k4][2], acc[i]);
        acc[i] = fmaf(xv.w, wreg[k4][3], acc[i]);
      }
    }
#pragma unroll
    for (int i = 0; i < 4; ++i) h[(r0 + rb + i) * 64 + col] = acc[i];
  }
}

// ---------------- in_proj: [16384x256] = h[16384x64] @ W[256x64]^T, split xp/z ----------------
__global__ __launch_bounds__(256) void k_inproj(const float* __restrict__ hin, const float* __restrict__ W,
                                                float* __restrict__ xp, float* __restrict__ z) {
  __shared__ __align__(16) float ht[64][68];
  __shared__ __align__(16) float wt[64][68];
  const int t = threadIdx.x;
  const int r0 = blockIdx.x * 64;
  const int c0 = blockIdx.y * 64;
  for (int idx = t; idx < 64 * 16; idx += 256) {
    int r = idx >> 4, k4 = idx & 15;
    float4 v = *(const float4*)(hin + (r0 + r) * 64 + 4 * k4);
    ht[4 * k4 + 0][r] = v.x; ht[4 * k4 + 1][r] = v.y; ht[4 * k4 + 2][r] = v.z; ht[4 * k4 + 3][r] = v.w;
  }
  for (int idx = t; idx < 64 * 16; idx += 256) {
    int c = idx >> 4, k4 = idx & 15;
    float4 v = *(const float4*)(W + (c0 + c) * 64 + 4 * k4);
    wt[4 * k4 + 0][c] = v.x; wt[4 * k4 + 1][c] = v.y; wt[4 * k4 + 2][c] = v.z; wt[4 * k4 + 3][c] = v.w;
  }
  __syncthreads();
  const int tc = t & 15, tr = t >> 4;
  float acc[4][4] = {};
  for (int k = 0; k < 64; ++k) {
    float4 a = *(const float4*)&ht[k][4 * tr];
    float4 b = *(const float4*)&wt[k][4 * tc];
    float av[4] = {a.x, a.y, a.z, a.w};
    float bv[4] = {b.x, b.y, b.z, b.w};
#pragma unroll
    for (int i = 0; i < 4; ++i)
#pragma unroll
      for (int j = 0; j < 4; ++j) acc[i][j] = fmaf(av[i], bv[j], acc[i][j]);
  }
#pragma unroll
  for (int i = 0; i < 4; ++i) {
    int row = r0 + 4 * tr + i;
    int c = c0 + 4 * tc;
    float4 v = make_float4(acc[i][0], acc[i][1], acc[i][2], acc[i][3]);
    if (c0 < 128) *(float4*)(xp + row * 128 + c) = v;
    else          *(float4*)(z + row * 128 + (c - 128)) = v;
  }
}

// ---------------- K_mid: conv+silu + x_proj + dt_proj + chunk-local scan ----------------
// LDS 38.5 KB -> 4 blocks/CU (16 waves/CU). Conv reads xp directly from global.
__global__ __launch_bounds__(256, 4) void k_mid(const float* __restrict__ xp, const float* __restrict__ cw,
                                                const float* __restrict__ cb, const float* __restrict__ xpw,
                                                const float* __restrict__ dpw, const float* __restrict__ dpb,
                                                const float* __restrict__ Alog,
                                                float* __restrict__ u_g, float* __restrict__ dl_g,
                                                float* __restrict__ B_g, float* __restrict__ C_g,
                                                float* __restrict__ chP, float* __restrict__ chH) {
  __shared__ __align__(16) float ush[16][132];
  __shared__ __align__(16) float dsh[16][132];
  __shared__ __align__(16) float wsh[36][132];
  __shared__ __align__(16) float dbl[16][40];

  const int t = threadIdx.x;
  const int c = blockIdx.x;          // chunk 0..255
  const int b = blockIdx.y;          // batch 0..3
  const int grow0 = b * SL + c * CT;

  // stage x_proj_w (no barrier needed before conv: wsh not read until after sync)
  for (int i = t; i < 36 * 128; i += 256) {
    int cc = i >> 7, dd = i & 127;
    wsh[cc][dd] = xpw[cc * 128 + dd];
  }
  // conv + silu -> u (direct global reads, coalesced; rows -1..-3 come from prev chunk)
  for (int i = t; i < 16 * 128; i += 256) {
    int r = i >> 7, dd = i & 127;
    float4 cwv = *(const float4*)(cw + dd * 4);
    const float* base = xp + (size_t)(grow0 + r) * 128 + dd;
    int l = c * CT + r;              // within-sequence index
    float acc = cb[dd] + base[0] * cwv.w;
    if (l >= 1) acc += base[-128] * cwv.z;
    if (l >= 2) acc += base[-256] * cwv.y;
    if (l >= 3) acc += base[-384] * cwv.x;
    float uu = siluf(acc);
    ush[r][dd] = uu;
    u_g[(size_t)(grow0 + r) * 128 + dd] = uu;
  }
  __syncthreads();

  // x_proj -> dbl[16][36] (144 tasks: 1 row x 4 cols each)
  if (t < 144) {
    int r = t / 9, cg = t - (t / 9) * 9;
    int cc = cg * 4;
    float a0 = 0, a1 = 0, a2 = 0, a3 = 0;
#pragma unroll 8
    for (int k4 = 0; k4 < 32; ++k4) {
      float4 uu = *(const float4*)&ush[r][4 * k4];
      float4 w0 = *(const float4*)&wsh[cc + 0][4 * k4];
      float4 w1 = *(const float4*)&wsh[cc + 1][4 * k4];
      float4 w2 = *(const float4*)&wsh[cc + 2][4 * k4];
      float4 w3 = *(const float4*)&wsh[cc + 3][4 * k4];
      a0 += uu.x * w0.x + uu.y * w0.y + uu.z * w0.z + uu.w * w0.w;
      a1 += uu.x * w1.x + uu.y * w1.y + uu.z * w1.z + uu.w * w1.w;
      a2 += uu.x * w2.x + uu.y * w2.y + uu.z * w2.z + uu.w * w2.w;
      a3 += uu.x * w3.x + uu.y * w3.y + uu.z * w3.z + uu.w * w3.w;
    }
    dbl[r][cc + 0] = a0; dbl[r][cc + 1] = a1; dbl[r][cc + 2] = a2; dbl[r][cc + 3] = a3;
  }
  __syncthreads();

  // dt_proj + softplus -> delta; export B/C
  for (int i = t; i < 16 * 128; i += 256) {
    int r = i >> 7, dd = i & 127;
    float4 wv = *(const float4*)(dpw + dd * 4);
    float acc = dpb[dd] + dbl[r][0] * wv.x + dbl[r][1] * wv.y + dbl[r][2] * wv.z + dbl[r][3] * wv.w;
    float dt = softplusf(acc);
    dsh[r][dd] = dt;
    dl_g[(size_t)(grow0 + r) * 128 + dd] = dt;
  }
  for (int i = t; i < 16 * 32; i += 256) {
    int r = i >> 5, j = i & 31;
    float v = dbl[r][4 + j];
    if (j < 16) B_g[(grow0 + r) * 16 + j] = v;
    else        C_g[(grow0 + r) * 16 + (j - 16)] = v;
  }
  __syncthreads();

  // chunk-local scan (thread = (d, half); 8 states each); B read from dbl (broadcast)
  {
    const int d = t & 127, hf = t >> 7, n0 = hf * 8;
    float a[8], hst[8];
#pragma unroll
    for (int j = 0; j < 8; ++j) {
      a[j] = -__expf(Alog[d * 16 + n0 + j]);
      hst[j] = 0.f;
    }
    float dts = 0.f;
#pragma unroll 4
    for (int tt = 0; tt < CT; ++tt) {
      float dt = dsh[tt][d];
      float du = dt * ush[tt][d];
      dts += dt;
#pragma unroll
      for (int j = 0; j < 8; ++j) {
        float e = __expf(dt * a[j]);
        hst[j] = fmaf(e, hst[j], du * dbl[tt][4 + n0 + j]);
      }
    }
    int off = ((b * 128 + d) * NC + c) * 16 + n0;
    float p[8];
#pragma unroll
    for (int j = 0; j < 8; ++j) p[j] = __expf(dts * a[j]);   // prod_t exp(dt*A) = exp(A*sum dt)
    *(float4*)(chP + off + 0) = make_float4(p[0], p[1], p[2], p[3]);
    *(float4*)(chP + off + 4) = make_float4(p[4], p[5], p[6], p[7]);
    *(float4*)(chH + off + 0) = make_float4(hst[0], hst[1], hst[2], hst[3]);
    *(float4*)(chH + off + 4) = make_float4(hst[4], hst[5], hst[6], hst[7]);
  }
}

// ---------------- scan2p: two-level carry propagation, block per (b,d) ----------------
__global__ __launch_bounds__(256) void k_scan2p(const float* __restrict__ chP, float* chH) {
  __shared__ float sP[16][16];   // [g][n]
  __shared__ float sH[16][16];
  const int t = threadIdx.x;
  const int n = t & 15, g = t >> 4;
  const int d = blockIdx.x, b = blockIdx.y;
  const int base = ((b * 128 + d) * NC) * 16 + n;

  float Pl[16], Hl[16];
  float cp = 1.f, ch = 0.f;
#pragma unroll
  for (int i = 0; i < 16; ++i) {
    int idx = base + (g * 16 + i) * 16;
    float P = chP[idx];
    float H = chH[idx];
    Pl[i] = P; Hl[i] = H;
    ch = fmaf(P, ch, H);
    cp *= P;
  }
  sP[g][n] = cp; sH[g][n] = ch;
  __syncthreads();
#pragma unroll
  for (int s = 1; s < 16; s <<= 1) {
    float pL = 1.f, hL = 0.f;
    if (g >= s) { pL = sP[g - s][n]; hL = sH[g - s][n]; }
    __syncthreads();
    ch = fmaf(cp, hL, ch);
    cp = cp * pL;
    sP[g][n] = cp; sH[g][n] = ch;
    __syncthreads();
  }
  float carry = 0.f;
  if (g > 0) carry = sH[g - 1][n];
#pragma unroll
  for (int i = 0; i < 16; ++i) {
    int idx = base + (g * 16 + i) * 16;
    chH[idx] = carry;
    carry = fmaf(Pl[i], carry, Hl[i]);
  }
}

// ---------------- K_back: scan replay + gate fused in-loop + full-K out_proj + residual -------
// LDS 29.2 KB -> 5 blocks/CU (20 waves/CU). Lane-paired state split, shfl_xor combine.
__global__ __launch_bounds__(256, 5) void k_back(const float* __restrict__ u_g, const float* __restrict__ dl_g,
                                                 const float* __restrict__ B_g, const float* __restrict__ C_g,
                                                 const float* __restrict__ z_g, const float* __restrict__ cin,
                                                 const float* __restrict__ Alog, const float* __restrict__ Dsk,
                                                 const float* __restrict__ opwT, float* __restrict__ h) {
  __shared__ __align__(16) float ush[16][132];
  __shared__ __align__(16) float dsh[16][132];
  __shared__ float bsh[16][16];
  __shared__ float csh[16][16];
  __shared__ __align__(16) float ygsh[128][20];

  const int t = threadIdx.x;
  const int c = blockIdx.x;
  const int b = blockIdx.y;
  const int grow0 = b * SL + c * CT;

  // stage u, delta, B, C
  for (int i = t; i < 16 * 128; i += 256) {
    int r = i >> 7, dd = i & 127;
    ush[r][dd] = u_g[(size_t)(grow0 + r) * 128 + dd];
    dsh[r][dd] = dl_g[(size_t)(grow0 + r) * 128 + dd];
  }
  for (int i = t; i < 16 * 32; i += 256) {
    int r = i >> 5, j = i & 31;
    if (j < 16) bsh[r][j] = B_g[(grow0 + r) * 16 + j];
    else        csh[r][j - 16] = C_g[(grow0 + r) * 16 + (j - 16)];
  }
  __syncthreads();

  // replay scan with carry-in + D-skip + silu(z) gate, lane pair (d = t>>1, hf = t&1)
  {
    const int d = t >> 1, hf = t & 1, n0 = hf * 8;
    float a[8], hst[8];
    size_t off = ((size_t)(b * 128 + d) * NC + c) * 16 + n0;
    float4 h0 = *(const float4*)(cin + off + 0);
    float4 h1 = *(const float4*)(cin + off + 4);
    hst[0] = h0.x; hst[1] = h0.y; hst[2] = h0.z; hst[3] = h0.w;
    hst[4] = h1.x; hst[5] = h1.y; hst[6] = h1.z; hst[7] = h1.w;
#pragma unroll
    for (int j = 0; j < 8; ++j) a[j] = -__expf(Alog[d * 16 + n0 + j]);
    const float Dd = Dsk[d];
#pragma unroll 4
    for (int tt = 0; tt < CT; ++tt) {
      float dt = dsh[tt][d];
      float ut = ush[tt][d];
      float du = dt * ut;
      float yv = 0.f;
#pragma unroll
      for (int j = 0; j < 8; ++j) {
        float e = __expf(dt * a[j]);
        hst[j] = fmaf(e, hst[j], du * bsh[tt][n0 + j]);
        yv = fmaf(hst[j], csh[tt][n0 + j], yv);
      }
      float tot = yv + __shfl_xor(yv, 1);   // both lanes execute (no divergence at shfl)
      if (hf == 0) {
        float y = tot + ut * Dd;
        float zv = z_g[(size_t)(grow0 + tt) * 128 + d];
        ygsh[d][tt] = y * siluf(zv);
      }
    }
  }
  __syncthreads();

  // out_proj full-K per thread + residual: o = t&63, q = t>>6 -> rows q*4..q*4+3
  {
    const int o = t & 63, q = t >> 6;
    float acc0 = 0.f, acc1 = 0.f, acc2 = 0.f, acc3 = 0.f;
#pragma unroll 8
    for (int k = 0; k < 128; ++k) {
      float w = opwT[k * 64 + o];
      float4 yv = *(const float4*)&ygsh[k][q * 4];
      acc0 = fmaf(yv.x, w, acc0);
      acc1 = fmaf(yv.y, w, acc1);
      acc2 = fmaf(yv.z, w, acc2);
      acc3 = fmaf(yv.w, w, acc3);
    }
    h[(size_t)(grow0 + q * 4 + 0) * 64 + o] += acc0;
    h[(size_t)(grow0 + q * 4 + 1) * 64 + o] += acc1;
    h[(size_t)(grow0 + q * 4 + 2) * 64 + o] += acc2;
    h[(size_t)(grow0 + q * 4 + 3) * 64 + o] += acc3;
  }
}

// ---------------- pooling partials over L ----------------
__global__ __launch_bounds__(256) void k_poolpart(const float* __restrict__ h, float* __restrict__ pp) {
  const int lb = blockIdx.x;
  const int b = blockIdx.y;
  const int t = threadIdx.x;
  const int d = t & 63, part = t >> 6;
  float s = 0.f;
  for (int i = 0; i < 32; ++i) {
    int l = lb * 128 + part + i * 4;
    s += h[(size_t)(b * SL + l) * 64 + d];
  }
  __shared__ float red[256];
  red[t] = s;
  __syncthreads();
  if (t < 64) pp[(b * 32 + lb) * 64 + t] = red[t] + red[t + 64] + red[t + 128] + red[t + 192];
}

// ---------------- final reduce + classifier ----------------
__global__ __launch_bounds__(256) void k_cls(const float* __restrict__ pp, const float* __restrict__ wc,
                                             const float* __restrict__ bc, float* __restrict__ out) {
  const int t = threadIdx.x;
  __shared__ float pooled[4][64];
  int b = t >> 6, d = t & 63;
  float s = 0.f;
  for (int lb = 0; lb < 32; ++lb) s += pp[(b * 32 + lb) * 64 + d];
  pooled[b][d] = s * (1.f / 4096.f);
  __syncthreads();
  if (t < 24) {
    int bb = t / 6, o = t - bb * 6;
    float acc = bc[o];
    for (int d2 = 0; d2 < 64; ++d2) acc += pooled[bb][d2] * wc[o * 64 + d2];
    out[bb * 6 + o] = acc;
  }
}

extern "C" void kernel_launch(void* const* d_in, const int* in_sizes, int n_in,
                              void* d_out, int out_size, void* d_ws, size_t ws_size,
                              hipStream_t stream) {
  const float* x    = (const float*)d_in[0];
  const float* w_in = (const float*)d_in[1];
  const float* b_in = (const float*)d_in[2];
  const float* ipw  = (const float*)d_in[3];
  const float* cw   = (const float*)d_in[4];
  const float* cb   = (const float*)d_in[5];
  const float* xpw  = (const float*)d_in[6];
  const float* dpw  = (const float*)d_in[7];
  const float* dpb  = (const float*)d_in[8];
  const float* Alog = (const float*)d_in[9];
  const float* Dsk  = (const float*)d_in[10];
  const float* opw  = (const float*)d_in[11];
  const float* wc   = (const float*)d_in[12];
  const float* bc   = (const float*)d_in[13];
  float* out = (float*)d_out;

  float* ws   = (float*)d_ws;
  float* h    = ws;                    // 1048576
  float* xp   = h + 1048576;           // 2097152
  float* zb   = xp + 2097152;          // 2097152
  float* ub   = zb + 2097152;          // 2097152
  float* dl   = ub + 2097152;          // 2097152
  float* Bb   = dl + 2097152;          // 262144
  float* Cb   = Bb + 262144;           // 262144
  float* chP  = Cb + 262144;           // 2097152
  float* chH  = chP + 2097152;         // 2097152 (becomes carry-in after k_scan2p)
  float* opwT = chH + 2097152;         // 16384
  float* pp   = opwT + 16384;          // 8192

  k_prep<<<64, 256, 0, stream>>>(opw, opwT);
  k_linin<<<256, 256, 0, stream>>>(x, w_in, b_in, h);
  for (int i = 0; i < 2; ++i) {
    k_inproj<<<dim3(256, 4), 256, 0, stream>>>(h, ipw + i * 16384, xp, zb);
    k_mid<<<dim3(NC, 4), 256, 0, stream>>>(xp, cw + i * 512, cb + i * 128,
                                           xpw + i * 4608, dpw + i * 512, dpb + i * 128,
                                           Alog + i * 2048, ub, dl, Bb, Cb, chP, chH);
    k_scan2p<<<dim3(128, 4), 256, 0, stream>>>(chP, chH);
    k_back<<<dim3(NC, 4), 256, 0, stream>>>(ub, dl, Bb, Cb, zb, chH,
                                            Alog + i * 2048, Dsk + i * 128,
                                            opwT + i * 8192, h);
  }
  k_poolpart<<<dim3(32, 4), 256, 0, stream>>>(h, pp);
  k_cls<<<1, 256, 0, stream>>>(pp, wc, bc, out);
}